// Round 7
// baseline (479.519 us; speedup 1.0000x reference)
//
#include <hip/hip_runtime.h>
#include <stdint.h>

#define DEVI static __device__ __forceinline__

typedef __attribute__((ext_vector_type(8))) __bf16 bf16x8;
typedef __attribute__((ext_vector_type(4))) float f32x4;

#define MFMA16(a, b, c) __builtin_amdgcn_mfma_f32_16x16x32_bf16((a), (b), (c), 0, 0, 0)

DEVI uint16_t f2bf(float f) {
  uint32_t u = __builtin_bit_cast(uint32_t, f);
  u += 0x7fffu + ((u >> 16) & 1u);   // RNE (no NaN inputs here)
  return (uint16_t)(u >> 16);
}

DEVI void gload16(const void* g, void* l) {
  __builtin_amdgcn_global_load_lds((const __attribute__((address_space(1))) void*)g,
                                   (__attribute__((address_space(3))) void*)l, 16, 0, 0);
}

#define BARRIER()                         \
  do {                                    \
    __builtin_amdgcn_sched_barrier(0);    \
    __builtin_amdgcn_s_barrier();         \
    __builtin_amdgcn_sched_barrier(0);    \
  } while (0)

// ---------------- W f32 [1024][1024] -> Wt bf16 [n][k] (transposed), 4 at once ----------------
struct W4 {
  const float* W[4];
  uint16_t* Wt[4];
};

__global__ __launch_bounds__(256) void wtrans4(W4 p) {
  __shared__ float t[64][65];
  const float* __restrict__ W = p.W[blockIdx.z];
  uint16_t* __restrict__ Wt = p.Wt[blockIdx.z];
  const int ti = blockIdx.y * 64, tj = blockIdx.x * 64;
  {
    int r = threadIdx.x >> 2, c0 = (threadIdx.x & 3) * 16;
#pragma unroll
    for (int i = 0; i < 16; i += 4) {
      float4 v = *(const float4*)(W + (size_t)(ti + r) * 1024 + tj + c0 + i);
      t[r][c0 + i + 0] = v.x; t[r][c0 + i + 1] = v.y;
      t[r][c0 + i + 2] = v.z; t[r][c0 + i + 3] = v.w;
    }
  }
  __syncthreads();
  {
    int c = threadIdx.x >> 2, r0 = (threadIdx.x & 3) * 16;
    union { uint16_t u[16]; uint4 v[2]; } b;
#pragma unroll
    for (int i = 0; i < 16; ++i) b.u[i] = f2bf(t[r0 + i][c]);
    uint16_t* dst = Wt + (size_t)(tj + c) * 1024 + ti + r0;
    *(uint4*)dst = b.v[0];
    *(uint4*)(dst + 8) = b.v[1];
  }
}

// ---------------- 256x256-tile GEMM, BK=64, 8 waves (r6 core, unchanged) ----------------
// LDS 160KB: A 3-deep x 32KB @0, B 2-deep x 32KB @98304. counted vmcnt(4).
// Swizzle: LDS[row][u16] = G[row][u16 ^ (row&7)] (proven: 0 bank conflicts).
__global__ __launch_bounds__(512, 2) void gemm256(const uint16_t* __restrict__ A,
                                                  const uint16_t* __restrict__ Bt,
                                                  const float* __restrict__ bias,
                                                  void* __restrict__ C, int cf32) {
  __shared__ uint8_t lds[163840];
  const int tid = threadIdx.x;
  const int l = tid & 63, w = tid >> 6;
  const int wr = w >> 2, wc = w & 3;
  const int lc = l & 15, lq = l >> 4;

  const int bid = blockIdx.y * 4 + blockIdx.x;
  const int swz = (bid & 7) * 64 + (bid >> 3);
  const size_t m0 = (size_t)(swz >> 2) * 256;
  const int n0 = (swz & 3) * 256;

  const uint8_t* Ab = (const uint8_t*)A + m0 * 2048;
  const uint8_t* Bb = (const uint8_t*)Bt + (size_t)n0 * 2048;

  const int srow = tid >> 3;
  const int susw = ((tid & 7) ^ (srow & 7)) * 16;

  auto stageA = [&](int sb, int kt) {
#pragma unroll
    for (int j = 0; j < 4; ++j)
      gload16(Ab + (size_t)(j * 64 + srow) * 2048 + kt * 128 + susw,
              lds + sb * 32768 + j * 8192 + w * 1024);
  };
  auto stageB = [&](int db, int kt) {
#pragma unroll
    for (int j = 0; j < 4; ++j)
      gload16(Bb + (size_t)(j * 64 + srow) * 2048 + kt * 128 + susw,
              lds + 98304 + db * 32768 + j * 8192 + w * 1024);
  };

  auto ldsA = [&](int sb, int mi, int kk) -> bf16x8 {
    const int row = wr * 128 + mi * 16 + lc;
    const int u = ((kk * 4 + lq) ^ (row & 7)) * 16;
    return *(const bf16x8*)(lds + sb * 32768 + row * 128 + u);
  };
  auto ldsB = [&](int db, int ni, int kk) -> bf16x8 {
    const int row = wc * 64 + ni * 16 + lc;
    const int u = ((kk * 4 + lq) ^ (row & 7)) * 16;
    return *(const bf16x8*)(lds + 98304 + db * 32768 + row * 128 + u);
  };

  f32x4 acc[8][4] = {};

  stageA(0, 0);
  stageB(0, 0);
  stageA(1, 1);
  asm volatile("s_waitcnt vmcnt(4)" ::: "memory");
  BARRIER();

  for (int t = 0; t < 16; ++t) {
    const int ab = t % 3;
    const int bb = t & 1;
    if (t + 1 < 16) stageB((t + 1) & 1, t + 1);
    if (t + 2 < 16) stageA((t + 2) % 3, t + 2);

#pragma unroll
    for (int kk = 0; kk < 2; ++kk) {
      bf16x8 bF[4], aF[8];
#pragma unroll
      for (int ni = 0; ni < 4; ++ni) bF[ni] = ldsB(bb, ni, kk);
#pragma unroll
      for (int mi = 0; mi < 8; ++mi) aF[mi] = ldsA(ab, mi, kk);
      __builtin_amdgcn_s_setprio(1);
#pragma unroll
      for (int mi = 0; mi < 8; ++mi)
#pragma unroll
        for (int ni = 0; ni < 4; ++ni)
          acc[mi][ni] = MFMA16(aF[mi], bF[ni], acc[mi][ni]);
      __builtin_amdgcn_s_setprio(0);
    }

    if (t < 14)       { asm volatile("s_waitcnt vmcnt(4)" ::: "memory"); }
    else if (t == 14) { asm volatile("s_waitcnt vmcnt(0)" ::: "memory"); }
    if (t < 15) BARRIER();
  }

#pragma unroll
  for (int mi = 0; mi < 8; ++mi) {
#pragma unroll
    for (int ni = 0; ni < 4; ++ni) {
      const int col = n0 + wc * 64 + ni * 16 + lc;
      const float bb2 = bias[col];
#pragma unroll
      for (int r = 0; r < 4; ++r) {
        const size_t row = m0 + wr * 128 + mi * 16 + lq * 4 + r;
        const float vv = acc[mi][ni][r] + bb2;
        if (cf32) ((float*)C)[row * 1024 + col] = vv;
        else      ((uint16_t*)C)[row * 1024 + col] = f2bf(vv);
      }
    }
  }
}

// ---------------- fused projection GEMM: A f32 reg-staged + convert (grid.z = 3) ----------
// LDS 128KB: A 2-deep x 32KB @0, B 2-deep x 32KB @65536. Per iter t:
// stageB(t+1) + loadA_f32(t+1) issued at top (sched_barrier-pinned), 64 MFMA
// of cover (~2500 cyc >> 900 HBM), then cvt+swizzled ds_write, lgkm0, barrier.
struct Proj3 {
  const float* A[3];
  const uint16_t* W[3];
  const float* b[3];
  uint16_t* C[3];
};

__global__ __launch_bounds__(512, 2) void gemm_proj3(Proj3 p) {
  __shared__ uint8_t lds[131072];
  const int tid = threadIdx.x;
  const int l = tid & 63, w = tid >> 6;
  const int wr = w >> 2, wc = w & 3;
  const int lc = l & 15, lq = l >> 4;
  const int z = blockIdx.z;

  const int bid = blockIdx.y * 4 + blockIdx.x;
  const int swz = (bid & 7) * 64 + (bid >> 3);
  const size_t m0 = (size_t)(swz >> 2) * 256;
  const int n0 = (swz & 3) * 256;

  const float* Af = p.A[z];
  const uint8_t* Bb = (const uint8_t*)p.W[z] + (size_t)n0 * 2048;
  const float* bias = p.b[z];
  uint16_t* C = p.C[z];

  const int srow = tid >> 3;
  const int susw = ((tid & 7) ^ (srow & 7)) * 16;
  auto stageB = [&](int db, int kt) {
#pragma unroll
    for (int j = 0; j < 4; ++j)
      gload16(Bb + (size_t)(j * 64 + srow) * 2048 + kt * 128 + susw,
              lds + 65536 + db * 32768 + j * 8192 + w * 1024);
  };

  // A reg-staging: instr j -> 4 rows (w*32+j*4+(l>>4)), 16 lanes/row x 16B = 256B row slab
  auto loadA = [&](int kt, float4 (&ra)[8]) {
#pragma unroll
    for (int j = 0; j < 8; ++j) {
      const int row = w * 32 + j * 4 + (l >> 4);
      ra[j] = *(const float4*)(Af + (m0 + row) * 1024 + kt * 64 + (l & 15) * 4);
    }
  };
  // write swizzled: G unit u lives at LDS unit u^(row&7)  (same invariant as gload path)
  auto writeA = [&](int sel, const float4 (&ra)[8]) {
#pragma unroll
    for (int j = 0; j < 8; ++j) {
      const int row = w * 32 + j * 4 + (l >> 4);
      const int u = (l & 15) >> 1;
      union { uint16_t h[4]; uint2 v; } tv;
      tv.h[0] = f2bf(ra[j].x); tv.h[1] = f2bf(ra[j].y);
      tv.h[2] = f2bf(ra[j].z); tv.h[3] = f2bf(ra[j].w);
      *(uint2*)(lds + sel * 32768 + row * 128 + ((u ^ (row & 7)) << 4) + (l & 1) * 8) = tv.v;
    }
  };

  auto ldsA = [&](int sb, int mi, int kk) -> bf16x8 {
    const int row = wr * 128 + mi * 16 + lc;
    const int u = ((kk * 4 + lq) ^ (row & 7)) * 16;
    return *(const bf16x8*)(lds + sb * 32768 + row * 128 + u);
  };
  auto ldsB = [&](int db, int ni, int kk) -> bf16x8 {
    const int row = wc * 64 + ni * 16 + lc;
    const int u = ((kk * 4 + lq) ^ (row & 7)) * 16;
    return *(const bf16x8*)(lds + 65536 + db * 32768 + row * 128 + u);
  };

  f32x4 acc[8][4] = {};

  // prologue: tile 0
  {
    float4 r0[8];
    loadA(0, r0);
    stageB(0, 0);
    writeA(0, r0);                                     // compiler waits ra's vmcnt
    asm volatile("s_waitcnt vmcnt(0)" ::: "memory");   // B(0) landed
    asm volatile("s_waitcnt lgkmcnt(0)" ::: "memory");
  }
  BARRIER();

  for (int t = 0; t < 16; ++t) {
    const int cur = t & 1;
    const bool more = (t + 1 < 16);
    float4 ra[8];
    if (more) {
      stageB(cur ^ 1, t + 1);
      loadA(t + 1, ra);
    }
    __builtin_amdgcn_sched_barrier(0);   // pin prefetch issue before compute

#pragma unroll
    for (int kk = 0; kk < 2; ++kk) {
      bf16x8 bF[4], aF[8];
#pragma unroll
      for (int ni = 0; ni < 4; ++ni) bF[ni] = ldsB(cur, ni, kk);
#pragma unroll
      for (int mi = 0; mi < 8; ++mi) aF[mi] = ldsA(cur, mi, kk);
      __builtin_amdgcn_s_setprio(1);
#pragma unroll
      for (int mi = 0; mi < 8; ++mi)
#pragma unroll
        for (int ni = 0; ni < 4; ++ni)
          acc[mi][ni] = MFMA16(aF[mi], bF[ni], acc[mi][ni]);
      __builtin_amdgcn_s_setprio(0);
    }

    if (more) {
      writeA(cur ^ 1, ra);                               // auto vmcnt wait on ra
      asm volatile("s_waitcnt vmcnt(0)" ::: "memory");   // B(t+1) landed too
      asm volatile("s_waitcnt lgkmcnt(0)" ::: "memory"); // ds_writes committed
      BARRIER();
    }
  }

#pragma unroll
  for (int mi = 0; mi < 8; ++mi) {
#pragma unroll
    for (int ni = 0; ni < 4; ++ni) {
      const int col = n0 + wc * 64 + ni * 16 + lc;
      const float bb2 = bias[col];
#pragma unroll
      for (int r = 0; r < 4; ++r) {
        const size_t row = m0 + wr * 128 + mi * 16 + lq * 4 + r;
        C[row * 1024 + col] = f2bf(acc[mi][ni][r] + bb2);
      }
    }
  }
}

// ---------------- block-diagonal attention ----------------
__global__ __launch_bounds__(256) void attn(const uint16_t* __restrict__ Qh,
                                            const uint16_t* __restrict__ Kh,
                                            const uint16_t* __restrict__ Vh,
                                            uint16_t* __restrict__ Oh,
                                            float* __restrict__ Wlast) {
  __shared__ uint16_t Ks[128][72];
  __shared__ uint16_t Vt[64][136];
  __shared__ uint16_t Ps[128][136];

  const int blk = blockIdx.x;
  const int b = blk >> 10;
  const int h = (blk >> 6) & 15;
  const int g = blk & 63;
  const size_t rowbase = (size_t)b * 8192 + (size_t)g * 128;
  const int colbase = h * 64;

  const int tid = threadIdx.x, lane = tid & 63, wv = tid >> 6;
  const int lc = lane & 15, lq = lane >> 4;
  const int m0 = wv * 32;

  {
    const int r = tid >> 1, hf = (tid & 1) * 32;
    const uint16_t* ksrc = Kh + (rowbase + r) * 1024 + colbase + hf;
    const uint16_t* vsrc = Vh + (rowbase + r) * 1024 + colbase + hf;
    union { uint16_t u[32]; uint4 v[4]; } kk, vb;
#pragma unroll
    for (int i = 0; i < 4; ++i) kk.v[i] = *(const uint4*)(ksrc + i * 8);
#pragma unroll
    for (int i = 0; i < 4; ++i) vb.v[i] = *(const uint4*)(vsrc + i * 8);
#pragma unroll
    for (int i = 0; i < 4; ++i) *(uint4*)&Ks[r][hf + i * 8] = kk.v[i];
#pragma unroll
    for (int j = 0; j < 32; ++j) Vt[hf + j][r] = vb.u[j];
  }

  bf16x8 aq[2][2];
#pragma unroll
  for (int mi = 0; mi < 2; ++mi)
#pragma unroll
    for (int ks = 0; ks < 2; ++ks)
      aq[mi][ks] = *(const bf16x8*)(Qh + (rowbase + m0 + mi * 16 + lc) * 1024 +
                                    colbase + ks * 32 + lq * 8);

  __syncthreads();

  f32x4 sacc[2][8] = {};
#pragma unroll
  for (int ks = 0; ks < 2; ++ks) {
#pragma unroll
    for (int ni = 0; ni < 8; ++ni) {
      bf16x8 bk = *(const bf16x8*)&Ks[ni * 16 + lc][ks * 32 + lq * 8];
      sacc[0][ni] = MFMA16(aq[0][ks], bk, sacc[0][ni]);
      sacc[1][ni] = MFMA16(aq[1][ks], bk, sacc[1][ni]);
    }
  }

  const float scale = 0.125f;
  float mx[2][4], sm[2][4];
#pragma unroll
  for (int mi = 0; mi < 2; ++mi)
#pragma unroll
    for (int r = 0; r < 4; ++r) {
      float m = -1e30f;
#pragma unroll
      for (int ni = 0; ni < 8; ++ni) m = fmaxf(m, sacc[mi][ni][r]);
      m = fmaxf(m, __shfl_xor(m, 1));
      m = fmaxf(m, __shfl_xor(m, 2));
      m = fmaxf(m, __shfl_xor(m, 4));
      m = fmaxf(m, __shfl_xor(m, 8));
      mx[mi][r] = m * scale;
    }
#pragma unroll
  for (int mi = 0; mi < 2; ++mi)
#pragma unroll
    for (int ni = 0; ni < 8; ++ni)
#pragma unroll
      for (int r = 0; r < 4; ++r)
        sacc[mi][ni][r] = __expf(sacc[mi][ni][r] * scale - mx[mi][r]);
#pragma unroll
  for (int mi = 0; mi < 2; ++mi)
#pragma unroll
    for (int r = 0; r < 4; ++r) {
      float s = 0.f;
#pragma unroll
      for (int ni = 0; ni < 8; ++ni) s += sacc[mi][ni][r];
      s += __shfl_xor(s, 1); s += __shfl_xor(s, 2);
      s += __shfl_xor(s, 4); s += __shfl_xor(s, 8);
      sm[mi][r] = 1.0f / s;
    }

#pragma unroll
  for (int mi = 0; mi < 2; ++mi)
#pragma unroll
    for (int ni = 0; ni < 8; ++ni)
#pragma unroll
      for (int r = 0; r < 4; ++r) {
        float wgt = sacc[mi][ni][r] * sm[mi][r];
        sacc[mi][ni][r] = wgt;
        Ps[m0 + mi * 16 + lq * 4 + r][ni * 16 + lc] = f2bf(wgt);
      }
  if (g == 63) {
    float* wl = Wlast + (size_t)(b * 16 + h) * 16384;
#pragma unroll
    for (int mi = 0; mi < 2; ++mi)
#pragma unroll
      for (int ni = 0; ni < 8; ++ni)
#pragma unroll
        for (int r = 0; r < 4; ++r)
          wl[(size_t)(m0 + mi * 16 + lq * 4 + r) * 128 + ni * 16 + lc] =
              sacc[mi][ni][r];
  }
  __syncthreads();

  f32x4 oacc[2][4] = {};
#pragma unroll
  for (int ks = 0; ks < 4; ++ks) {
    bf16x8 ap[2], bq[4];
#pragma unroll
    for (int mi = 0; mi < 2; ++mi)
      ap[mi] = *(const bf16x8*)&Ps[m0 + mi * 16 + lc][ks * 32 + lq * 8];
#pragma unroll
    for (int ni = 0; ni < 4; ++ni)
      bq[ni] = *(const bf16x8*)&Vt[ni * 16 + lc][ks * 32 + lq * 8];
#pragma unroll
    for (int mi = 0; mi < 2; ++mi)
#pragma unroll
      for (int ni = 0; ni < 4; ++ni)
        oacc[mi][ni] = MFMA16(ap[mi], bq[ni], oacc[mi][ni]);
  }
#pragma unroll
  for (int mi = 0; mi < 2; ++mi)
#pragma unroll
    for (int ni = 0; ni < 4; ++ni)
#pragma unroll
      for (int r = 0; r < 4; ++r)
        Oh[(rowbase + m0 + mi * 16 + lq * 4 + r) * 1024 + colbase + ni * 16 + lc] =
            f2bf(oacc[mi][ni][r]);
}

extern "C" void kernel_launch(void* const* d_in, const int* in_sizes, int n_in,
                              void* d_out, int out_size, void* d_ws, size_t ws_size,
                              hipStream_t stream) {
  (void)in_sizes; (void)n_in; (void)out_size; (void)ws_size;
  const float* q  = (const float*)d_in[0];
  const float* k  = (const float*)d_in[1];
  const float* v  = (const float*)d_in[2];
  const float* Wq = (const float*)d_in[3];
  const float* bq = (const float*)d_in[4];
  const float* Wk = (const float*)d_in[5];
  const float* bk = (const float*)d_in[6];
  const float* Wv = (const float*)d_in[7];
  const float* bv = (const float*)d_in[8];
  const float* Wo = (const float*)d_in[9];
  const float* bo = (const float*)d_in[10];

  uint8_t* ws = (uint8_t*)d_ws;
  const size_t WSZ = (size_t)1024 * 1024 * 2;   // 2 MB per transposed weight
  const size_t TSZ = (size_t)32768 * 1024 * 2;  // 64 MB per bf16 activation
  uint16_t* Wtq = (uint16_t*)(ws + 0 * WSZ);
  uint16_t* Wtk = (uint16_t*)(ws + 1 * WSZ);
  uint16_t* Wtv = (uint16_t*)(ws + 2 * WSZ);
  uint16_t* Wto = (uint16_t*)(ws + 3 * WSZ);
  uint16_t* Qh  = (uint16_t*)(ws + 4 * WSZ);
  uint16_t* Khp = (uint16_t*)(ws + 4 * WSZ + 1 * TSZ);
  uint16_t* Vhp = (uint16_t*)(ws + 4 * WSZ + 2 * TSZ);
  uint16_t* Xs  = (uint16_t*)(ws + 4 * WSZ + 3 * TSZ);  // attn-out (bf16)

  W4 wt;
  wt.W[0] = Wq; wt.W[1] = Wk; wt.W[2] = Wv; wt.W[3] = Wo;
  wt.Wt[0] = Wtq; wt.Wt[1] = Wtk; wt.Wt[2] = Wtv; wt.Wt[3] = Wto;
  wtrans4<<<dim3(16, 16, 4), 256, 0, stream>>>(wt);

  Proj3 p;
  p.A[0] = q;  p.A[1] = k;  p.A[2] = v;
  p.W[0] = Wtq; p.W[1] = Wtk; p.W[2] = Wtv;
  p.b[0] = bq; p.b[1] = bk; p.b[2] = bv;
  p.C[0] = Qh; p.C[1] = Khp; p.C[2] = Vhp;
  gemm_proj3<<<dim3(4, 128, 3), 512, 0, stream>>>(p);

  float* outp = (float*)d_out;
  attn<<<4096, 256, 0, stream>>>(Qh, Khp, Vhp, Xs, outp + (size_t)32768 * 1024);
  gemm256<<<dim3(4, 128), 512, 0, stream>>>(Xs, Wto, bo, outp, 1);
}

// Round 8
// 471.212 us; speedup vs baseline: 1.0176x; 1.0176x over previous
//
#include <hip/hip_runtime.h>
#include <stdint.h>

#define DEVI static __device__ __forceinline__

typedef __attribute__((ext_vector_type(8))) __bf16 bf16x8;
typedef __attribute__((ext_vector_type(4))) float f32x4;

#define MFMA16(a, b, c) __builtin_amdgcn_mfma_f32_16x16x32_bf16((a), (b), (c), 0, 0, 0)

DEVI uint16_t f2bf(float f) {
  uint32_t u = __builtin_bit_cast(uint32_t, f);
  u += 0x7fffu + ((u >> 16) & 1u);   // RNE (no NaN inputs here)
  return (uint16_t)(u >> 16);
}

DEVI void gload16(const void* g, void* l) {
  __builtin_amdgcn_global_load_lds((const __attribute__((address_space(1))) void*)g,
                                   (__attribute__((address_space(3))) void*)l, 16, 0, 0);
}

#define BARRIER()                         \
  do {                                    \
    __builtin_amdgcn_sched_barrier(0);    \
    __builtin_amdgcn_s_barrier();         \
    __builtin_amdgcn_sched_barrier(0);    \
  } while (0)

#define LGKM0_FENCE()                                      \
  do {                                                     \
    asm volatile("s_waitcnt lgkmcnt(0)" ::: "memory");     \
    __builtin_amdgcn_sched_barrier(0);                     \
  } while (0)

// ---------------- f32 -> bf16 convert (8 elems/thread) ----------------
__global__ __launch_bounds__(256) void cvt_bf16(const float* __restrict__ in,
                                                uint16_t* __restrict__ out, long n) {
  long i = ((long)blockIdx.x * 256 + threadIdx.x) * 8;
  if (i >= n) return;
  float4 a = *(const float4*)(in + i);
  float4 b = *(const float4*)(in + i + 4);
  union { uint16_t u[8]; uint4 v; } r;
  r.u[0] = f2bf(a.x); r.u[1] = f2bf(a.y); r.u[2] = f2bf(a.z); r.u[3] = f2bf(a.w);
  r.u[4] = f2bf(b.x); r.u[5] = f2bf(b.y); r.u[6] = f2bf(b.z); r.u[7] = f2bf(b.w);
  *(uint4*)(out + i) = r.v;
}

// ---------------- W f32 [1024][1024] -> Wt bf16 [n][k] (transposed), 4 at once ----------------
struct W4 {
  const float* W[4];
  uint16_t* Wt[4];
};

__global__ __launch_bounds__(256) void wtrans4(W4 p) {
  __shared__ float t[64][65];
  const float* __restrict__ W = p.W[blockIdx.z];
  uint16_t* __restrict__ Wt = p.Wt[blockIdx.z];
  const int ti = blockIdx.y * 64, tj = blockIdx.x * 64;
  {
    int r = threadIdx.x >> 2, c0 = (threadIdx.x & 3) * 16;
#pragma unroll
    for (int i = 0; i < 16; i += 4) {
      float4 v = *(const float4*)(W + (size_t)(ti + r) * 1024 + tj + c0 + i);
      t[r][c0 + i + 0] = v.x; t[r][c0 + i + 1] = v.y;
      t[r][c0 + i + 2] = v.z; t[r][c0 + i + 3] = v.w;
    }
  }
  __syncthreads();
  {
    int c = threadIdx.x >> 2, r0 = (threadIdx.x & 3) * 16;
    union { uint16_t u[16]; uint4 v[2]; } b;
#pragma unroll
    for (int i = 0; i < 16; ++i) b.u[i] = f2bf(t[r0 + i][c]);
    uint16_t* dst = Wt + (size_t)(tj + c) * 1024 + ti + r0;
    *(uint4*)dst = b.v[0];
    *(uint4*)(dst + 8) = b.v[1];
  }
}

// ---------------- 256x256-tile GEMM, BK=64, 8 waves, 4-phase/K-tile (m201 graft) ----------
// Buffers (r6-proven): A 3-deep x 32KB @0, B 2-deep x 32KB @98304; vmcnt(4)/iter.
// Swizzle (proven, 0 conflicts): LDS[row][u16] = G[row][u16 ^ (row&7)].
// Per K-tile: 4 phases of {ds_read subtile + stage 1 half-tile -> BAR ->
// lgkmcnt(0)+sched_barrier -> setprio1 -> 16 MFMA -> setprio0 -> BAR};
// register-frag reuse across phases: reads/phase = 12/4/8/0.
__global__ __launch_bounds__(512, 2) void gemm256(const uint16_t* __restrict__ A,
                                                  const uint16_t* __restrict__ Bt,
                                                  const float* __restrict__ bias,
                                                  void* __restrict__ C, int cf32) {
  __shared__ uint8_t lds[163840];
  const int tid = threadIdx.x;
  const int l = tid & 63, w = tid >> 6;
  const int wr = w >> 2, wc = w & 3;     // 2 x 4 wave grid
  const int lc = l & 15, lq = l >> 4;

  const int bid = blockIdx.y * 4 + blockIdx.x;
  const int swz = (bid & 7) * 64 + (bid >> 3);
  const size_t m0 = (size_t)(swz >> 2) * 256;
  const int n0 = (swz & 3) * 256;

  const uint8_t* Ab = (const uint8_t*)A + m0 * 2048;
  const uint8_t* Bb = (const uint8_t*)Bt + (size_t)n0 * 2048;

  const int srow = tid >> 3;
  const int susw = ((tid & 7) ^ (srow & 7)) * 16;

  // stage one 16KB half-tile (chunks 2h, 2h+1); 2 gload_lds per thread
  auto stageA_h = [&](int sb, int kt, int h) {
#pragma unroll
    for (int j = 2 * h; j < 2 * h + 2; ++j)
      gload16(Ab + (size_t)(j * 64 + srow) * 2048 + kt * 128 + susw,
              lds + sb * 32768 + j * 8192 + w * 1024);
  };
  auto stageB_h = [&](int db, int kt, int h) {
#pragma unroll
    for (int j = 2 * h; j < 2 * h + 2; ++j)
      gload16(Bb + (size_t)(j * 64 + srow) * 2048 + kt * 128 + susw,
              lds + 98304 + db * 32768 + j * 8192 + w * 1024);
  };

  auto ldsA = [&](int sb, int mi, int kk) -> bf16x8 {
    const int row = wr * 128 + mi * 16 + lc;
    const int u = ((kk * 4 + lq) ^ (row & 7)) * 16;
    return *(const bf16x8*)(lds + sb * 32768 + row * 128 + u);
  };
  auto ldsB = [&](int db, int ni, int kk) -> bf16x8 {
    const int row = wc * 64 + ni * 16 + lc;
    const int u = ((kk * 4 + lq) ^ (row & 7)) * 16;
    return *(const bf16x8*)(lds + 98304 + db * 32768 + row * 128 + u);
  };

  f32x4 acc[8][4] = {};

  // prologue: A(0), B(0), A(1); drain A0+B0, keep A1 in flight
  stageA_h(0, 0, 0); stageA_h(0, 0, 1);
  stageB_h(0, 0, 0); stageB_h(0, 0, 1);
  stageA_h(1, 1, 0); stageA_h(1, 1, 1);
  asm volatile("s_waitcnt vmcnt(4)" ::: "memory");
  BARRIER();

  for (int t = 0; t < 16; ++t) {
    const int ab = t % 3;
    const int bb = t & 1;
    const int nbB = (t + 1) & 1;
    const int nbA = (t + 2) % 3;
    const bool stB = (t + 1) < 16;
    const bool stA = (t + 2) < 16;

    bf16x8 aF[4][2], bF[4][2], aG[4][2];

    // ---- P0: read aF(mi0-3)x2kk + bF(ni0-1)x2kk (12); stage B(t+1) h0 ----
#pragma unroll
    for (int kk = 0; kk < 2; ++kk) {
#pragma unroll
      for (int mi = 0; mi < 4; ++mi) aF[mi][kk] = ldsA(ab, mi, kk);
#pragma unroll
      for (int ni = 0; ni < 2; ++ni) bF[ni][kk] = ldsB(bb, ni, kk);
    }
    if (stB) stageB_h(nbB, t + 1, 0);
    BARRIER();
    LGKM0_FENCE();
    __builtin_amdgcn_s_setprio(1);
#pragma unroll
    for (int mi = 0; mi < 4; ++mi)
#pragma unroll
      for (int ni = 0; ni < 2; ++ni) {
        acc[mi][ni] = MFMA16(aF[mi][0], bF[ni][0], acc[mi][ni]);
        acc[mi][ni] = MFMA16(aF[mi][1], bF[ni][1], acc[mi][ni]);
      }
    __builtin_amdgcn_s_setprio(0);
    BARRIER();

    // ---- P1: read bF(ni2-3)x2kk (4); stage B(t+1) h1; MFMA mi0-3 x ni2-3 ----
#pragma unroll
    for (int kk = 0; kk < 2; ++kk)
#pragma unroll
      for (int ni = 2; ni < 4; ++ni) bF[ni][kk] = ldsB(bb, ni, kk);
    if (stB) stageB_h(nbB, t + 1, 1);
    BARRIER();
    LGKM0_FENCE();
    __builtin_amdgcn_s_setprio(1);
#pragma unroll
    for (int mi = 0; mi < 4; ++mi)
#pragma unroll
      for (int ni = 2; ni < 4; ++ni) {
        acc[mi][ni] = MFMA16(aF[mi][0], bF[ni][0], acc[mi][ni]);
        acc[mi][ni] = MFMA16(aF[mi][1], bF[ni][1], acc[mi][ni]);
      }
    __builtin_amdgcn_s_setprio(0);
    BARRIER();

    // ---- P2: read aG(mi4-7)x2kk (8); stage A(t+2) h0; MFMA mi4-7 x ni0-1 ----
#pragma unroll
    for (int kk = 0; kk < 2; ++kk)
#pragma unroll
      for (int mi = 0; mi < 4; ++mi) aG[mi][kk] = ldsA(ab, mi + 4, kk);
    if (stA) stageA_h(nbA, t + 2, 0);
    BARRIER();
    LGKM0_FENCE();
    __builtin_amdgcn_s_setprio(1);
#pragma unroll
    for (int mi = 0; mi < 4; ++mi)
#pragma unroll
      for (int ni = 0; ni < 2; ++ni) {
        acc[mi + 4][ni] = MFMA16(aG[mi][0], bF[ni][0], acc[mi + 4][ni]);
        acc[mi + 4][ni] = MFMA16(aG[mi][1], bF[ni][1], acc[mi + 4][ni]);
      }
    __builtin_amdgcn_s_setprio(0);
    BARRIER();

    // ---- P3: stage A(t+2) h1; MFMA mi4-7 x ni2-3 (frags all in regs) ----
    if (stA) stageA_h(nbA, t + 2, 1);
    BARRIER();
    __builtin_amdgcn_s_setprio(1);
#pragma unroll
    for (int mi = 0; mi < 4; ++mi)
#pragma unroll
      for (int ni = 2; ni < 4; ++ni) {
        acc[mi + 4][ni] = MFMA16(aG[mi][0], bF[ni][0], acc[mi + 4][ni]);
        acc[mi + 4][ni] = MFMA16(aG[mi][1], bF[ni][1], acc[mi + 4][ni]);
      }
    __builtin_amdgcn_s_setprio(0);

    // end-of-iter counted wait: drain B(t+1) (oldest), keep A(t+2) in flight
    if (t < 14)       { asm volatile("s_waitcnt vmcnt(4)" ::: "memory"); }
    else if (t == 14) { asm volatile("s_waitcnt vmcnt(0)" ::: "memory"); }
    if (t < 15) BARRIER();
  }

  // epilogue: bias + store
#pragma unroll
  for (int mi = 0; mi < 8; ++mi) {
#pragma unroll
    for (int ni = 0; ni < 4; ++ni) {
      const int col = n0 + wc * 64 + ni * 16 + lc;
      const float bb2 = bias[col];
#pragma unroll
      for (int r = 0; r < 4; ++r) {
        const size_t row = m0 + wr * 128 + mi * 16 + lq * 4 + r;
        const float vv = acc[mi][ni][r] + bb2;
        if (cf32) ((float*)C)[row * 1024 + col] = vv;
        else      ((uint16_t*)C)[row * 1024 + col] = f2bf(vv);
      }
    }
  }
}

// ---------------- block-diagonal attention ----------------
__global__ __launch_bounds__(256) void attn(const uint16_t* __restrict__ Qh,
                                            const uint16_t* __restrict__ Kh,
                                            const uint16_t* __restrict__ Vh,
                                            uint16_t* __restrict__ Oh,
                                            float* __restrict__ Wlast) {
  __shared__ uint16_t Ks[128][72];
  __shared__ uint16_t Vt[64][136];
  __shared__ uint16_t Ps[128][136];

  const int blk = blockIdx.x;
  const int b = blk >> 10;
  const int h = (blk >> 6) & 15;
  const int g = blk & 63;
  const size_t rowbase = (size_t)b * 8192 + (size_t)g * 128;
  const int colbase = h * 64;

  const int tid = threadIdx.x, lane = tid & 63, wv = tid >> 6;
  const int lc = lane & 15, lq = lane >> 4;
  const int m0 = wv * 32;

  {
    const int r = tid >> 1, hf = (tid & 1) * 32;
    const uint16_t* ksrc = Kh + (rowbase + r) * 1024 + colbase + hf;
    const uint16_t* vsrc = Vh + (rowbase + r) * 1024 + colbase + hf;
    union { uint16_t u[32]; uint4 v[4]; } kk, vb;
#pragma unroll
    for (int i = 0; i < 4; ++i) kk.v[i] = *(const uint4*)(ksrc + i * 8);
#pragma unroll
    for (int i = 0; i < 4; ++i) vb.v[i] = *(const uint4*)(vsrc + i * 8);
#pragma unroll
    for (int i = 0; i < 4; ++i) *(uint4*)&Ks[r][hf + i * 8] = kk.v[i];
#pragma unroll
    for (int j = 0; j < 32; ++j) Vt[hf + j][r] = vb.u[j];
  }

  bf16x8 aq[2][2];
#pragma unroll
  for (int mi = 0; mi < 2; ++mi)
#pragma unroll
    for (int ks = 0; ks < 2; ++ks)
      aq[mi][ks] = *(const bf16x8*)(Qh + (rowbase + m0 + mi * 16 + lc) * 1024 +
                                    colbase + ks * 32 + lq * 8);

  __syncthreads();

  f32x4 sacc[2][8] = {};
#pragma unroll
  for (int ks = 0; ks < 2; ++ks) {
#pragma unroll
    for (int ni = 0; ni < 8; ++ni) {
      bf16x8 bk = *(const bf16x8*)&Ks[ni * 16 + lc][ks * 32 + lq * 8];
      sacc[0][ni] = MFMA16(aq[0][ks], bk, sacc[0][ni]);
      sacc[1][ni] = MFMA16(aq[1][ks], bk, sacc[1][ni]);
    }
  }

  const float scale = 0.125f;
  float mx[2][4], sm[2][4];
#pragma unroll
  for (int mi = 0; mi < 2; ++mi)
#pragma unroll
    for (int r = 0; r < 4; ++r) {
      float m = -1e30f;
#pragma unroll
      for (int ni = 0; ni < 8; ++ni) m = fmaxf(m, sacc[mi][ni][r]);
      m = fmaxf(m, __shfl_xor(m, 1));
      m = fmaxf(m, __shfl_xor(m, 2));
      m = fmaxf(m, __shfl_xor(m, 4));
      m = fmaxf(m, __shfl_xor(m, 8));
      mx[mi][r] = m * scale;
    }
#pragma unroll
  for (int mi = 0; mi < 2; ++mi)
#pragma unroll
    for (int ni = 0; ni < 8; ++ni)
#pragma unroll
      for (int r = 0; r < 4; ++r)
        sacc[mi][ni][r] = __expf(sacc[mi][ni][r] * scale - mx[mi][r]);
#pragma unroll
  for (int mi = 0; mi < 2; ++mi)
#pragma unroll
    for (int r = 0; r < 4; ++r) {
      float s = 0.f;
#pragma unroll
      for (int ni = 0; ni < 8; ++ni) s += sacc[mi][ni][r];
      s += __shfl_xor(s, 1); s += __shfl_xor(s, 2);
      s += __shfl_xor(s, 4); s += __shfl_xor(s, 8);
      sm[mi][r] = 1.0f / s;
    }

#pragma unroll
  for (int mi = 0; mi < 2; ++mi)
#pragma unroll
    for (int ni = 0; ni < 8; ++ni)
#pragma unroll
      for (int r = 0; r < 4; ++r) {
        float wgt = sacc[mi][ni][r] * sm[mi][r];
        sacc[mi][ni][r] = wgt;
        Ps[m0 + mi * 16 + lq * 4 + r][ni * 16 + lc] = f2bf(wgt);
      }
  if (g == 63) {
    float* wl = Wlast + (size_t)(b * 16 + h) * 16384;
#pragma unroll
    for (int mi = 0; mi < 2; ++mi)
#pragma unroll
      for (int ni = 0; ni < 8; ++ni)
#pragma unroll
        for (int r = 0; r < 4; ++r)
          wl[(size_t)(m0 + mi * 16 + lq * 4 + r) * 128 + ni * 16 + lc] =
              sacc[mi][ni][r];
  }
  __syncthreads();

  f32x4 oacc[2][4] = {};
#pragma unroll
  for (int ks = 0; ks < 4; ++ks) {
    bf16x8 ap[2], bq[4];
#pragma unroll
    for (int mi = 0; mi < 2; ++mi)
      ap[mi] = *(const bf16x8*)&Ps[m0 + mi * 16 + lc][ks * 32 + lq * 8];
#pragma unroll
    for (int ni = 0; ni < 4; ++ni)
      bq[ni] = *(const bf16x8*)&Vt[ni * 16 + lc][ks * 32 + lq * 8];
#pragma unroll
    for (int mi = 0; mi < 2; ++mi)
#pragma unroll
      for (int ni = 0; ni < 4; ++ni)
        oacc[mi][ni] = MFMA16(ap[mi], bq[ni], oacc[mi][ni]);
  }
#pragma unroll
  for (int mi = 0; mi < 2; ++mi)
#pragma unroll
    for (int ni = 0; ni < 4; ++ni)
#pragma unroll
      for (int r = 0; r < 4; ++r)
        Oh[(rowbase + m0 + mi * 16 + lq * 4 + r) * 1024 + colbase + ni * 16 + lc] =
            f2bf(oacc[mi][ni][r]);
}

extern "C" void kernel_launch(void* const* d_in, const int* in_sizes, int n_in,
                              void* d_out, int out_size, void* d_ws, size_t ws_size,
                              hipStream_t stream) {
  (void)in_sizes; (void)n_in; (void)out_size; (void)ws_size;
  const float* q  = (const float*)d_in[0];
  const float* k  = (const float*)d_in[1];
  const float* v  = (const float*)d_in[2];
  const float* Wq = (const float*)d_in[3];
  const float* bq = (const float*)d_in[4];
  const float* Wk = (const float*)d_in[5];
  const float* bk = (const float*)d_in[6];
  const float* Wv = (const float*)d_in[7];
  const float* bv = (const float*)d_in[8];
  const float* Wo = (const float*)d_in[9];
  const float* bo = (const float*)d_in[10];

  uint8_t* ws = (uint8_t*)d_ws;
  const size_t WSZ = (size_t)1024 * 1024 * 2;   // 2 MB per transposed weight
  const size_t TSZ = (size_t)32768 * 1024 * 2;  // 64 MB per bf16 activation
  uint16_t* Wtq = (uint16_t*)(ws + 0 * WSZ);
  uint16_t* Wtk = (uint16_t*)(ws + 1 * WSZ);
  uint16_t* Wtv = (uint16_t*)(ws + 2 * WSZ);
  uint16_t* Wto = (uint16_t*)(ws + 3 * WSZ);
  uint16_t* Qh  = (uint16_t*)(ws + 4 * WSZ);
  uint16_t* Khp = (uint16_t*)(ws + 4 * WSZ + 1 * TSZ);
  uint16_t* Vhp = (uint16_t*)(ws + 4 * WSZ + 2 * TSZ);
  uint16_t* Xs  = (uint16_t*)(ws + 4 * WSZ + 3 * TSZ);  // staging / attn-out

  W4 wt;
  wt.W[0] = Wq; wt.W[1] = Wk; wt.W[2] = Wv; wt.W[3] = Wo;
  wt.Wt[0] = Wtq; wt.Wt[1] = Wtk; wt.Wt[2] = Wtv; wt.Wt[3] = Wto;
  wtrans4<<<dim3(16, 16, 4), 256, 0, stream>>>(wt);

  const long NE = (long)32768 * 1024;
  const dim3 gg(4, 128), gb(512);
  cvt_bf16<<<16384, 256, 0, stream>>>(q, Xs, NE);
  gemm256<<<gg, gb, 0, stream>>>(Xs, Wtq, bq, Qh, 0);
  cvt_bf16<<<16384, 256, 0, stream>>>(k, Xs, NE);
  gemm256<<<gg, gb, 0, stream>>>(Xs, Wtk, bk, Khp, 0);
  cvt_bf16<<<16384, 256, 0, stream>>>(v, Xs, NE);
  gemm256<<<gg, gb, 0, stream>>>(Xs, Wtv, bv, Vhp, 0);

  float* outp = (float*)d_out;
  attn<<<4096, 256, 0, stream>>>(Qh, Khp, Vhp, Xs, outp + (size_t)32768 * 1024);
  gemm256<<<gg, gb, 0, stream>>>(Xs, Wto, bo, outp, 1);
}

// Round 9
// 467.256 us; speedup vs baseline: 1.0262x; 1.0085x over previous
//
#include <hip/hip_runtime.h>
#include <stdint.h>

#define DEVI static __device__ __forceinline__

typedef __attribute__((ext_vector_type(8))) __bf16 bf16x8;
typedef __attribute__((ext_vector_type(4))) float f32x4;

#define MFMA16(a, b, c) __builtin_amdgcn_mfma_f32_16x16x32_bf16((a), (b), (c), 0, 0, 0)

DEVI uint16_t f2bf(float f) {
  uint32_t u = __builtin_bit_cast(uint32_t, f);
  u += 0x7fffu + ((u >> 16) & 1u);   // RNE (no NaN inputs here)
  return (uint16_t)(u >> 16);
}

DEVI void gload16(const void* g, void* l) {
  __builtin_amdgcn_global_load_lds((const __attribute__((address_space(1))) void*)g,
                                   (__attribute__((address_space(3))) void*)l, 16, 0, 0);
}

#define BARRIER()                         \
  do {                                    \
    __builtin_amdgcn_sched_barrier(0);    \
    __builtin_amdgcn_s_barrier();         \
    __builtin_amdgcn_sched_barrier(0);    \
  } while (0)

#define LGKM0_FENCE()                                      \
  do {                                                     \
    asm volatile("s_waitcnt lgkmcnt(0)" ::: "memory");     \
    __builtin_amdgcn_sched_barrier(0);                     \
  } while (0)

// ---------------- f32 -> bf16 convert (8 elems/thread) ----------------
__global__ __launch_bounds__(256) void cvt_bf16(const float* __restrict__ in,
                                                uint16_t* __restrict__ out, long n) {
  long i = ((long)blockIdx.x * 256 + threadIdx.x) * 8;
  if (i >= n) return;
  float4 a = *(const float4*)(in + i);
  float4 b = *(const float4*)(in + i + 4);
  union { uint16_t u[8]; uint4 v; } r;
  r.u[0] = f2bf(a.x); r.u[1] = f2bf(a.y); r.u[2] = f2bf(a.z); r.u[3] = f2bf(a.w);
  r.u[4] = f2bf(b.x); r.u[5] = f2bf(b.y); r.u[6] = f2bf(b.z); r.u[7] = f2bf(b.w);
  *(uint4*)(out + i) = r.v;
}

// ---------------- W f32 [1024][1024] -> Wt bf16 [n][k] (transposed), 4 at once ----------------
struct W4 {
  const float* W[4];
  uint16_t* Wt[4];
};

__global__ __launch_bounds__(256) void wtrans4(W4 p) {
  __shared__ float t[64][65];
  const float* __restrict__ W = p.W[blockIdx.z];
  uint16_t* __restrict__ Wt = p.Wt[blockIdx.z];
  const int ti = blockIdx.y * 64, tj = blockIdx.x * 64;
  {
    int r = threadIdx.x >> 2, c0 = (threadIdx.x & 3) * 16;
#pragma unroll
    for (int i = 0; i < 16; i += 4) {
      float4 v = *(const float4*)(W + (size_t)(ti + r) * 1024 + tj + c0 + i);
      t[r][c0 + i + 0] = v.x; t[r][c0 + i + 1] = v.y;
      t[r][c0 + i + 2] = v.z; t[r][c0 + i + 3] = v.w;
    }
  }
  __syncthreads();
  {
    int c = threadIdx.x >> 2, r0 = (threadIdx.x & 3) * 16;
    union { uint16_t u[16]; uint4 v[2]; } b;
#pragma unroll
    for (int i = 0; i < 16; ++i) b.u[i] = f2bf(t[r0 + i][c]);
    uint16_t* dst = Wt + (size_t)(tj + c) * 1024 + ti + r0;
    *(uint4*)dst = b.v[0];
    *(uint4*)(dst + 8) = b.v[1];
  }
}

// ---------------- 128x128-tile GEMM, BK=64, 4 waves, 3 blocks/CU ----------------
// C[M][1024] = A[M][1024] @ Bt^T (+bias).  A,Bt bf16; C f32 or bf16.
// Occupancy-first structure (m97-family): LDS 48KB = A dbuf 2x16KB @0 +
// B single 16KB @32768.  Per K-tile(64): read B-frags -> lgkm0 -> BAR ->
// restage B(t+1) in place + A(t+1) -> alt buf -> MFMA (A-frags per kk) ->
// vmcnt(0) -> BAR.  3 independent blocks/CU cover each other's stalls (m114).
// Swizzle (proven, 0 conflicts): LDS[row][u16] = G[row][u16 ^ (row&7)];
// inverse on global_load_lds SOURCE, forward on ds_read.
__global__ __launch_bounds__(256, 3) void gemm128(const uint16_t* __restrict__ A,
                                                  const uint16_t* __restrict__ Bt,
                                                  const float* __restrict__ bias,
                                                  void* __restrict__ C, int cf32) {
  __shared__ uint8_t lds[49152];
  const int tid = threadIdx.x;
  const int l = tid & 63, w = tid >> 6;
  const int wr = w >> 1, wc = w & 1;     // 2 x 2 wave grid, 64x64 per wave
  const int lc = l & 15, lq = l >> 4;

  // bijective XCD swizzle over 2048 blocks: XCD c owns m-panels [c*32,(c+1)*32),
  // n-fast within panel (8 n-blocks of one A-panel co-resident -> A L2-hot)
  const int bid = blockIdx.y * 8 + blockIdx.x;
  const int swz = (bid & 7) * 256 + (bid >> 3);
  const size_t m0 = (size_t)(swz >> 3) * 128;
  const int n0 = (swz & 7) * 128;

  const uint8_t* Ab = (const uint8_t*)A + m0 * 2048;
  const uint8_t* Bb = (const uint8_t*)Bt + (size_t)n0 * 2048;

  // staging: chunk c = w*4+j = 1KB = 8 rows x 128B; lane covers 16B
  const int lrow = l >> 3;                 // row within chunk == row&7
  const int susw = ((l & 7) ^ lrow) * 16;  // inverse-swizzled source unit

  auto stageA = [&](int buf, int kt) {
#pragma unroll
    for (int j = 0; j < 4; ++j) {
      const int c = w * 4 + j;
      gload16(Ab + (size_t)(c * 8 + lrow) * 2048 + kt * 128 + susw,
              lds + buf * 16384 + c * 1024);
    }
  };
  auto stageB = [&](int kt) {
#pragma unroll
    for (int j = 0; j < 4; ++j) {
      const int c = w * 4 + j;
      gload16(Bb + (size_t)(c * 8 + lrow) * 2048 + kt * 128 + susw,
              lds + 32768 + c * 1024);
    }
  };

  auto ldsA = [&](int buf, int mi, int kk) -> bf16x8 {
    const int row = wr * 64 + mi * 16 + lc;
    const int u = ((kk * 4 + lq) ^ (row & 7)) * 16;
    return *(const bf16x8*)(lds + buf * 16384 + row * 128 + u);
  };
  auto ldsB = [&](int ni, int kk) -> bf16x8 {
    const int row = wc * 64 + ni * 16 + lc;
    const int u = ((kk * 4 + lq) ^ (row & 7)) * 16;
    return *(const bf16x8*)(lds + 32768 + row * 128 + u);
  };

  f32x4 acc[4][4] = {};

  // prologue: tile 0
  stageA(0, 0);
  stageB(0);
  asm volatile("s_waitcnt vmcnt(0)" ::: "memory");
  BARRIER();

  for (int t = 0; t < 16; ++t) {
    const int cur = t & 1;
    const bool more = (t + 1 < 16);

    // read ALL B-frags to regs (B buffer is restaged in place below)
    bf16x8 bF[4][2];
#pragma unroll
    for (int ni = 0; ni < 4; ++ni)
#pragma unroll
      for (int kk = 0; kk < 2; ++kk) bF[ni][kk] = ldsB(ni, kk);
    LGKM0_FENCE();
    BARRIER();   // every wave's B-reads complete before any restage lands

    if (more) {
      stageB(t + 1);            // in-place (safe: B now in regs block-wide)
      stageA(cur ^ 1, t + 1);   // alt buffer
    }

#pragma unroll
    for (int kk = 0; kk < 2; ++kk) {
      bf16x8 aF[4];
#pragma unroll
      for (int mi = 0; mi < 4; ++mi) aF[mi] = ldsA(cur, mi, kk);
      __builtin_amdgcn_s_setprio(1);
#pragma unroll
      for (int mi = 0; mi < 4; ++mi)
#pragma unroll
        for (int ni = 0; ni < 4; ++ni)
          acc[mi][ni] = MFMA16(aF[mi], bF[ni][kk], acc[mi][ni]);
      __builtin_amdgcn_s_setprio(0);
    }

    if (more) {
      asm volatile("s_waitcnt vmcnt(0)" ::: "memory");  // t+1 tiles landed
      BARRIER();
    }
  }

  // epilogue: bias + store
#pragma unroll
  for (int mi = 0; mi < 4; ++mi) {
#pragma unroll
    for (int ni = 0; ni < 4; ++ni) {
      const int col = n0 + wc * 64 + ni * 16 + lc;
      const float bb = bias[col];
#pragma unroll
      for (int r = 0; r < 4; ++r) {
        const size_t row = m0 + wr * 64 + mi * 16 + lq * 4 + r;
        const float vv = acc[mi][ni][r] + bb;
        if (cf32) ((float*)C)[row * 1024 + col] = vv;
        else      ((uint16_t*)C)[row * 1024 + col] = f2bf(vv);
      }
    }
  }
}

// ---------------- block-diagonal attention ----------------
__global__ __launch_bounds__(256) void attn(const uint16_t* __restrict__ Qh,
                                            const uint16_t* __restrict__ Kh,
                                            const uint16_t* __restrict__ Vh,
                                            uint16_t* __restrict__ Oh,
                                            float* __restrict__ Wlast) {
  __shared__ uint16_t Ks[128][72];
  __shared__ uint16_t Vt[64][136];
  __shared__ uint16_t Ps[128][136];

  const int blk = blockIdx.x;
  const int b = blk >> 10;
  const int h = (blk >> 6) & 15;
  const int g = blk & 63;
  const size_t rowbase = (size_t)b * 8192 + (size_t)g * 128;
  const int colbase = h * 64;

  const int tid = threadIdx.x, lane = tid & 63, wv = tid >> 6;
  const int lc = lane & 15, lq = lane >> 4;
  const int m0 = wv * 32;

  {
    const int r = tid >> 1, hf = (tid & 1) * 32;
    const uint16_t* ksrc = Kh + (rowbase + r) * 1024 + colbase + hf;
    const uint16_t* vsrc = Vh + (rowbase + r) * 1024 + colbase + hf;
    union { uint16_t u[32]; uint4 v[4]; } kk, vb;
#pragma unroll
    for (int i = 0; i < 4; ++i) kk.v[i] = *(const uint4*)(ksrc + i * 8);
#pragma unroll
    for (int i = 0; i < 4; ++i) vb.v[i] = *(const uint4*)(vsrc + i * 8);
#pragma unroll
    for (int i = 0; i < 4; ++i) *(uint4*)&Ks[r][hf + i * 8] = kk.v[i];
#pragma unroll
    for (int j = 0; j < 32; ++j) Vt[hf + j][r] = vb.u[j];
  }

  bf16x8 aq[2][2];
#pragma unroll
  for (int mi = 0; mi < 2; ++mi)
#pragma unroll
    for (int ks = 0; ks < 2; ++ks)
      aq[mi][ks] = *(const bf16x8*)(Qh + (rowbase + m0 + mi * 16 + lc) * 1024 +
                                    colbase + ks * 32 + lq * 8);

  __syncthreads();

  f32x4 sacc[2][8] = {};
#pragma unroll
  for (int ks = 0; ks < 2; ++ks) {
#pragma unroll
    for (int ni = 0; ni < 8; ++ni) {
      bf16x8 bk = *(const bf16x8*)&Ks[ni * 16 + lc][ks * 32 + lq * 8];
      sacc[0][ni] = MFMA16(aq[0][ks], bk, sacc[0][ni]);
      sacc[1][ni] = MFMA16(aq[1][ks], bk, sacc[1][ni]);
    }
  }

  const float scale = 0.125f;
  float mx[2][4], sm[2][4];
#pragma unroll
  for (int mi = 0; mi < 2; ++mi)
#pragma unroll
    for (int r = 0; r < 4; ++r) {
      float m = -1e30f;
#pragma unroll
      for (int ni = 0; ni < 8; ++ni) m = fmaxf(m, sacc[mi][ni][r]);
      m = fmaxf(m, __shfl_xor(m, 1));
      m = fmaxf(m, __shfl_xor(m, 2));
      m = fmaxf(m, __shfl_xor(m, 4));
      m = fmaxf(m, __shfl_xor(m, 8));
      mx[mi][r] = m * scale;
    }
#pragma unroll
  for (int mi = 0; mi < 2; ++mi)
#pragma unroll
    for (int ni = 0; ni < 8; ++ni)
#pragma unroll
      for (int r = 0; r < 4; ++r)
        sacc[mi][ni][r] = __expf(sacc[mi][ni][r] * scale - mx[mi][r]);
#pragma unroll
  for (int mi = 0; mi < 2; ++mi)
#pragma unroll
    for (int r = 0; r < 4; ++r) {
      float s = 0.f;
#pragma unroll
      for (int ni = 0; ni < 8; ++ni) s += sacc[mi][ni][r];
      s += __shfl_xor(s, 1); s += __shfl_xor(s, 2);
      s += __shfl_xor(s, 4); s += __shfl_xor(s, 8);
      sm[mi][r] = 1.0f / s;
    }

#pragma unroll
  for (int mi = 0; mi < 2; ++mi)
#pragma unroll
    for (int ni = 0; ni < 8; ++ni)
#pragma unroll
      for (int r = 0; r < 4; ++r) {
        float wgt = sacc[mi][ni][r] * sm[mi][r];
        sacc[mi][ni][r] = wgt;
        Ps[m0 + mi * 16 + lq * 4 + r][ni * 16 + lc] = f2bf(wgt);
      }
  if (g == 63) {
    float* wl = Wlast + (size_t)(b * 16 + h) * 16384;
#pragma unroll
    for (int mi = 0; mi < 2; ++mi)
#pragma unroll
      for (int ni = 0; ni < 8; ++ni)
#pragma unroll
        for (int r = 0; r < 4; ++r)
          wl[(size_t)(m0 + mi * 16 + lq * 4 + r) * 128 + ni * 16 + lc] =
              sacc[mi][ni][r];
  }
  __syncthreads();

  f32x4 oacc[2][4] = {};
#pragma unroll
  for (int ks = 0; ks < 4; ++ks) {
    bf16x8 ap[2], bq[4];
#pragma unroll
    for (int mi = 0; mi < 2; ++mi)
      ap[mi] = *(const bf16x8*)&Ps[m0 + mi * 16 + lc][ks * 32 + lq * 8];
#pragma unroll
    for (int ni = 0; ni < 4; ++ni)
      bq[ni] = *(const bf16x8*)&Vt[ni * 16 + lc][ks * 32 + lq * 8];
#pragma unroll
    for (int mi = 0; mi < 2; ++mi)
#pragma unroll
      for (int ni = 0; ni < 4; ++ni)
        oacc[mi][ni] = MFMA16(ap[mi], bq[ni], oacc[mi][ni]);
  }
#pragma unroll
  for (int mi = 0; mi < 2; ++mi)
#pragma unroll
    for (int ni = 0; ni < 4; ++ni)
#pragma unroll
      for (int r = 0; r < 4; ++r)
        Oh[(rowbase + m0 + mi * 16 + lq * 4 + r) * 1024 + colbase + ni * 16 + lc] =
            f2bf(oacc[mi][ni][r]);
}

extern "C" void kernel_launch(void* const* d_in, const int* in_sizes, int n_in,
                              void* d_out, int out_size, void* d_ws, size_t ws_size,
                              hipStream_t stream) {
  (void)in_sizes; (void)n_in; (void)out_size; (void)ws_size;
  const float* q  = (const float*)d_in[0];
  const float* k  = (const float*)d_in[1];
  const float* v  = (const float*)d_in[2];
  const float* Wq = (const float*)d_in[3];
  const float* bq = (const float*)d_in[4];
  const float* Wk = (const float*)d_in[5];
  const float* bk = (const float*)d_in[6];
  const float* Wv = (const float*)d_in[7];
  const float* bv = (const float*)d_in[8];
  const float* Wo = (const float*)d_in[9];
  const float* bo = (const float*)d_in[10];

  uint8_t* ws = (uint8_t*)d_ws;
  const size_t WSZ = (size_t)1024 * 1024 * 2;   // 2 MB per transposed weight
  const size_t TSZ = (size_t)32768 * 1024 * 2;  // 64 MB per bf16 activation
  uint16_t* Wtq = (uint16_t*)(ws + 0 * WSZ);
  uint16_t* Wtk = (uint16_t*)(ws + 1 * WSZ);
  uint16_t* Wtv = (uint16_t*)(ws + 2 * WSZ);
  uint16_t* Wto = (uint16_t*)(ws + 3 * WSZ);
  uint16_t* Qh  = (uint16_t*)(ws + 4 * WSZ);
  uint16_t* Khp = (uint16_t*)(ws + 4 * WSZ + 1 * TSZ);
  uint16_t* Vhp = (uint16_t*)(ws + 4 * WSZ + 2 * TSZ);
  uint16_t* Xs  = (uint16_t*)(ws + 4 * WSZ + 3 * TSZ);  // staging / attn-out

  W4 wt;
  wt.W[0] = Wq; wt.W[1] = Wk; wt.W[2] = Wv; wt.W[3] = Wo;
  wt.Wt[0] = Wtq; wt.Wt[1] = Wtk; wt.Wt[2] = Wtv; wt.Wt[3] = Wto;
  wtrans4<<<dim3(16, 16, 4), 256, 0, stream>>>(wt);

  const long NE = (long)32768 * 1024;
  const dim3 gg(8, 256), gb(256);
  cvt_bf16<<<16384, 256, 0, stream>>>(q, Xs, NE);
  gemm128<<<gg, gb, 0, stream>>>(Xs, Wtq, bq, Qh, 0);
  cvt_bf16<<<16384, 256, 0, stream>>>(k, Xs, NE);
  gemm128<<<gg, gb, 0, stream>>>(Xs, Wtk, bk, Khp, 0);
  cvt_bf16<<<16384, 256, 0, stream>>>(v, Xs, NE);
  gemm128<<<gg, gb, 0, stream>>>(Xs, Wtv, bv, Vhp, 0);

  float* outp = (float*)d_out;
  attn<<<4096, 256, 0, stream>>>(Qh, Khp, Vhp, Xs, outp + (size_t)32768 * 1024);
  gemm128<<<gg, gb, 0, stream>>>(Xs, Wto, bo, outp, 1);
}